// Round 1
// baseline (294.508 us; speedup 1.0000x reference)
//
#include <hip/hip_runtime.h>
#include <math.h>

#define IEPS 1e-8f

__global__ __launch_bounds__(256) void iou3d_loss_kernel(
    const float* __restrict__ pred, const float* __restrict__ target,
    double* __restrict__ acc, int N)
{
    int i = blockIdx.x * blockDim.x + threadIdx.x;
    float val = 0.0f;
    if (i < N) {
        const float* b1 = pred   + (size_t)i * 7;
        const float* b2 = target + (size_t)i * 7;
        float x1 = b1[0], y1 = b1[1], z1 = b1[2], w1 = b1[3], h1 = b1[4], dz1 = b1[5], a1 = b1[6];
        float x2 = b2[0], y2 = b2[1], z2 = b2[2], w2 = b2[3], h2 = b2[4], dz2 = b2[5], a2 = b2[6];

        // ---- box2corners ----
        const float sx4[4] = {0.5f, -0.5f, -0.5f, 0.5f};
        const float sy4[4] = {0.5f, 0.5f, -0.5f, -0.5f};
        float c1x[4], c1y[4], c2x[4], c2y[4];
        {
            float sn, cs;
            sincosf(a1, &sn, &cs);
            #pragma unroll
            for (int k = 0; k < 4; k++) {
                float px = sx4[k] * w1, py = sy4[k] * h1;
                c1x[k] = px * cs - py * sn + x1;
                c1y[k] = px * sn + py * cs + y1;
            }
            sincosf(a2, &sn, &cs);
            #pragma unroll
            for (int k = 0; k < 4; k++) {
                float px = sx4[k] * w2, py = sy4[k] * h2;
                c2x[k] = px * cs - py * sn + x2;
                c2y[k] = px * sn + py * cs + y2;
            }
        }

        // ---- 24 candidate vertices ----
        float vx[24], vy[24];
        unsigned vmask = 0;

        // corners of box1 in box2  (vertices 0..3)
        {
            float abx = c2x[1] - c2x[0], aby = c2y[1] - c2y[0];
            float adx = c2x[3] - c2x[0], ady = c2y[3] - c2y[0];
            float dab = abx * abx + aby * aby;
            float dad = adx * adx + ady * ady;
            const float e = 1e-6f;
            #pragma unroll
            for (int k = 0; k < 4; k++) {
                float amx = c1x[k] - c2x[0], amy = c1y[k] - c2y[0];
                float pab = (amx * abx + amy * aby) / dab;
                float pad = (amx * adx + amy * ady) / dad;
                bool m = (pab > -e) & (pab < 1.f + e) & (pad > -e) & (pad < 1.f + e);
                vx[k] = c1x[k];
                vy[k] = c1y[k];
                vmask |= ((unsigned)m) << k;
            }
        }
        // corners of box2 in box1  (vertices 4..7)
        {
            float abx = c1x[1] - c1x[0], aby = c1y[1] - c1y[0];
            float adx = c1x[3] - c1x[0], ady = c1y[3] - c1y[0];
            float dab = abx * abx + aby * aby;
            float dad = adx * adx + ady * ady;
            const float e = 1e-6f;
            #pragma unroll
            for (int k = 0; k < 4; k++) {
                float amx = c2x[k] - c1x[0], amy = c2y[k] - c1y[0];
                float pab = (amx * abx + amy * aby) / dab;
                float pad = (amx * adx + amy * ady) / dad;
                bool m = (pab > -e) & (pab < 1.f + e) & (pad > -e) & (pad < 1.f + e);
                vx[4 + k] = c2x[k];
                vy[4 + k] = c2y[k];
                vmask |= ((unsigned)m) << (4 + k);
            }
        }
        // edge-edge intersections (vertices 8..23), index 8 + ii*4 + jj
        #pragma unroll
        for (int ii = 0; ii < 4; ii++) {
            float p1x = c1x[ii], p1y = c1y[ii];
            float rx = c1x[(ii + 1) & 3] - p1x, ry = c1y[(ii + 1) & 3] - p1y;
            #pragma unroll
            for (int jj = 0; jj < 4; jj++) {
                float p2x = c2x[jj], p2y = c2y[jj];
                float sx = c2x[(jj + 1) & 3] - p2x, sy = c2y[(jj + 1) & 3] - p2y;
                float den = (rx * sy - ry * sx) + IEPS;
                float dpx = p2x - p1x, dpy = p2y - p1y;
                float t = (dpx * sy - dpy * sx) / den;
                float u = (dpx * ry - dpy * rx) / den;
                bool m = (t > 0.f) & (t < 1.f) & (u > 0.f) & (u < 1.f);
                int k = 8 + ii * 4 + jj;
                vx[k] = m ? (p1x + t * rx) : 0.f;
                vy[k] = m ? (p1y + t * ry) : 0.f;
                vmask |= ((unsigned)m) << k;
            }
        }

        // ---- mean of valid vertices ----
        float sumx = 0.f, sumy = 0.f;
        int nv = 0;
        #pragma unroll
        for (int k = 0; k < 24; k++) {
            bool m = (vmask >> k) & 1u;
            sumx += m ? vx[k] : 0.f;
            sumy += m ? vy[k] : 0.f;
            nv += (int)m;
        }
        float dn = (float)(nv > 1 ? nv : 1);
        float mx = sumx / dn, my = sumy / dn;

        // ---- center + diamond pseudo-angle (NaN for invalid) ----
        float ang[24];
        #pragma unroll
        for (int k = 0; k < 24; k++) {
            bool m = (vmask >> k) & 1u;
            float x = m ? (vx[k] - mx) : 0.f;
            float y = m ? (vy[k] - my) : 0.f;
            vx[k] = x;
            vy[k] = y;
            float t = y / (fabsf(x) + fabsf(y));   // NaN if x==y==0
            float a = (x >= 0.f) ? t : ((y >= 0.f) ? 2.f - t : -2.f - t);
            ang[k] = m ? a : __int_as_float(0x7fc00000);  // NaN excludes invalid
        }

        // ---- cyclic-successor shoelace sum ----
        // total = sum over valid i of cross(v_i, v_succ(i)) where succ is the
        // next vertex in ascending cyclic (pseudo-)angle order. Equals the
        // reference's sorted shoelace + closing edge exactly.
        float total = 0.f;
        #pragma unroll
        for (int ii = 0; ii < 24; ii++) {
            float ai = ang[ii];
            float best = 1e30f;
            float sx = 0.f, sy = 0.f;
            #pragma unroll
            for (int jj = 0; jj < 24; jj++) {
                if (jj == ii) continue;
                float d = ang[jj] - ai;           // NaN-propagating
                d = (d <= 0.f) ? d + 4.f : d;     // wraparound (period 4)
                bool c = (d < best);              // false if NaN
                best = c ? d : best;
                sx = c ? vx[jj] : sx;
                sy = c ? vy[jj] : sy;
            }
            total += vx[ii] * sy - vy[ii] * sx;   // 0 for invalid ii (vx=vy=0)
        }
        float area = fabsf(total) * 0.5f;

        // ---- z overlap + volumes ----
        float zmax1 = z1 + dz1 * 0.5f, zmin1 = z1 - dz1 * 0.5f;
        float zmax2 = z2 + dz2 * 0.5f, zmin2 = z2 - dz2 * 0.5f;
        float zo = fminf(zmax1, zmax2) - fmaxf(zmin1, zmin2);
        zo = fmaxf(zo, 0.f);
        float inter3d = area * zo;
        float vol1 = w1 * h1 * dz1;
        float vol2 = w2 * h2 * dz2;
        float union3d = vol1 + vol2 - inter3d;
        val = 1.f - inter3d / union3d;
    }

    // ---- block reduction -> double atomic ----
    #pragma unroll
    for (int off = 32; off > 0; off >>= 1)
        val += __shfl_down(val, off, 64);
    __shared__ float wsum[4];
    int lane = threadIdx.x & 63, wid = threadIdx.x >> 6;
    if (lane == 0) wsum[wid] = val;
    __syncthreads();
    if (threadIdx.x == 0) {
        float s = wsum[0] + wsum[1] + wsum[2] + wsum[3];
        atomicAdd(acc, (double)s);
    }
}

__global__ void iou3d_finalize_kernel(const double* __restrict__ acc,
                                      float* __restrict__ out, int N)
{
    out[0] = (float)(acc[0] / (double)N);
}

extern "C" void kernel_launch(void* const* d_in, const int* in_sizes, int n_in,
                              void* d_out, int out_size, void* d_ws, size_t ws_size,
                              hipStream_t stream) {
    const float* pred   = (const float*)d_in[0];
    const float* target = (const float*)d_in[1];
    int N = in_sizes[0] / 7;
    double* acc = (double*)d_ws;

    hipMemsetAsync(d_ws, 0, sizeof(double), stream);

    int block = 256;
    int grid = (N + block - 1) / block;
    iou3d_loss_kernel<<<grid, block, 0, stream>>>(pred, target, acc, N);
    iou3d_finalize_kernel<<<1, 1, 0, stream>>>(acc, (float*)d_out, N);
}

// Round 2
// 66.925 us; speedup vs baseline: 4.4006x; 4.4006x over previous
//
#include <hip/hip_runtime.h>
#include <math.h>

// Branchless Sutherland-Hodgman intersection area for two convex quads.
// Each clip stage emits exactly 2 output slots per input edge:
//   q0 = crossing ? C : (in(a) ? a : proj_L(a))
//   q1 = in(b) ? b : proj_L(b)
// Placeholder points lie ON the clip line, so any chain of them telescopes
// out of the shoelace sum (cross terms of collinear points depend only on the
// chain endpoints, which are the true entry/exit crossings). Hence the
// shoelace of the output equals the shoelace of the true clipped polygon,
// with no compaction, no sorting, no dynamic indexing.

struct Clip { float ex, ey, c0, inv; };  // d(p) = ex*py - ey*px + c0 ; inside = d >= 0 (CCW)

__device__ __forceinline__ Clip mk_clip(float e0x, float e0y, float e1x, float e1y) {
    Clip c;
    c.ex = e1x - e0x; c.ey = e1y - e0y;
    c.c0 = c.ey * e0x - c.ex * e0y;
    float nn = c.ex * c.ex + c.ey * c.ey;
    c.inv = 1.0f / fmaxf(nn, 1e-30f);   // guard zero-length edge (degenerate box)
    return c;
}
__device__ __forceinline__ float clip_d(const Clip& c, float px, float py) {
    return fmaf(c.ex, py, fmaf(-c.ey, px, c.c0));
}
// v if inside, else projection of v onto the clip line
__device__ __forceinline__ void vin_of(const Clip& c, float px, float py, float d, bool in,
                                       float& ox, float& oy) {
    float s = d * c.inv;
    float qx = fmaf(s, c.ey, px);
    float qy = fmaf(-s, c.ex, py);
    ox = in ? px : qx;
    oy = in ? py : qy;
}

template<int N>
__device__ __forceinline__ void clip_stage(const Clip& c,
                                           const float (&ix)[N], const float (&iy)[N],
                                           float (&ox)[2 * N], float (&oy)[2 * N]) {
    float d[N], vx_[N], vy_[N];
    bool in[N];
    #pragma unroll
    for (int k = 0; k < N; k++) {
        d[k] = clip_d(c, ix[k], iy[k]);
        in[k] = d[k] >= 0.0f;
        vin_of(c, ix[k], iy[k], d[k], in[k], vx_[k], vy_[k]);
    }
    #pragma unroll
    for (int k = 0; k < N; k++) {
        const int kn = (k + 1) % N;
        float t  = d[k] * __builtin_amdgcn_rcpf(d[k] - d[kn]);  // in [0,1] when crossing
        float Cx = fmaf(t, ix[kn] - ix[k], ix[k]);
        float Cy = fmaf(t, iy[kn] - iy[k], iy[k]);
        bool cr = in[k] != in[kn];
        ox[2 * k]     = cr ? Cx : vx_[k];
        oy[2 * k]     = cr ? Cy : vy_[k];
        ox[2 * k + 1] = vx_[kn];
        oy[2 * k + 1] = vy_[kn];
    }
}

__global__ __launch_bounds__(256) void iou3d_loss_kernel(
    const float* __restrict__ pred, const float* __restrict__ target,
    double* __restrict__ acc_out, int N)
{
    int i = blockIdx.x * blockDim.x + threadIdx.x;
    float val = 0.0f;
    if (i < N) {
        const float* b1 = pred   + (size_t)i * 7;
        const float* b2 = target + (size_t)i * 7;
        float x1 = b1[0], y1 = b1[1], z1 = b1[2], w1 = b1[3], h1 = b1[4], dz1 = b1[5], a1 = b1[6];
        float x2 = b2[0], y2 = b2[1], z2 = b2[2], w2 = b2[3], h2 = b2[4], dz2 = b2[5], a2 = b2[6];

        // ---- corners (CCW) ----
        const float sx4[4] = {0.5f, -0.5f, -0.5f, 0.5f};
        const float sy4[4] = {0.5f, 0.5f, -0.5f, -0.5f};
        float c1x[4], c1y[4], c2x[4], c2y[4];
        {
            float sn, cs;
            sincosf(a1, &sn, &cs);
            #pragma unroll
            for (int k = 0; k < 4; k++) {
                float px = sx4[k] * w1, py = sy4[k] * h1;
                c1x[k] = px * cs - py * sn + x1;
                c1y[k] = px * sn + py * cs + y1;
            }
            sincosf(a2, &sn, &cs);
            #pragma unroll
            for (int k = 0; k < 4; k++) {
                float px = sx4[k] * w2, py = sy4[k] * h2;
                c2x[k] = px * cs - py * sn + x2;
                c2y[k] = px * sn + py * cs + y2;
            }
        }

        Clip cl0 = mk_clip(c2x[0], c2y[0], c2x[1], c2y[1]);
        Clip cl1 = mk_clip(c2x[1], c2y[1], c2x[2], c2y[2]);
        Clip cl2 = mk_clip(c2x[2], c2y[2], c2x[3], c2y[3]);
        Clip cl3 = mk_clip(c2x[3], c2y[3], c2x[0], c2y[0]);

        // ---- stage 1: 4 -> 8 ; stage 2: 8 -> 16 (materialized) ----
        float s1x[8], s1y[8];
        clip_stage<4>(cl0, c1x, c1y, s1x, s1y);
        float s2x[16], s2y[16];
        clip_stage<8>(cl1, s1x, s1y, s2x, s2y);

        // ---- stage 3 (cl2) streamed into stage 4 (cl3) + shoelace ----
        float acc = 0.0f;

        // stage-3 per-vertex state for vertex 0 (and wrap copies)
        float dA = clip_d(cl2, s2x[0], s2y[0]);
        bool  iA = dA >= 0.0f;
        float vAx, vAy; vin_of(cl2, s2x[0], s2y[0], dA, iA, vAx, vAy);
        float d0s = dA; bool i0s = iA; float v0x = vAx, v0y = vAy;
        float ax = s2x[0], ay = s2y[0];

        // stage-4 stream state
        float px = 0.f, py = 0.f, dp = 0.f, pvx = 0.f, pvy = 0.f; bool pin = false;
        float opx = 0.f, opy = 0.f, ofx = 0.f, ofy = 0.f;
        float fsx = 0.f, fsy = 0.f;  // first stage-3 output (for wrap)

        #define SINIT(VX, VY) do { \
            px = (VX); py = (VY); \
            dp = clip_d(cl3, (VX), (VY)); \
            pin = dp >= 0.0f; \
            vin_of(cl3, (VX), (VY), dp, pin, pvx, pvy); \
        } while (0)

        #define PUSH(VX, VY, FIRSTOUT) do { \
            float dv = clip_d(cl3, (VX), (VY)); \
            bool inv_ = dv >= 0.0f; \
            float vvx, vvy; vin_of(cl3, (VX), (VY), dv, inv_, vvx, vvy); \
            float t_ = dp * __builtin_amdgcn_rcpf(dp - dv); \
            float Cx_ = fmaf(t_, (VX) - px, px); \
            float Cy_ = fmaf(t_, (VY) - py, py); \
            bool cr_ = (pin != inv_); \
            float q0x = cr_ ? Cx_ : pvx; \
            float q0y = cr_ ? Cy_ : pvy; \
            if (FIRSTOUT) { ofx = q0x; ofy = q0y; } \
            else { acc = fmaf(opx, q0y, acc); acc = fmaf(-opy, q0x, acc); } \
            acc = fmaf(q0x, vvy, acc); acc = fmaf(-q0y, vvx, acc); \
            opx = vvx; opy = vvy; \
            px = (VX); py = (VY); dp = dv; pvx = vvx; pvy = vvy; pin = inv_; \
        } while (0)

        #pragma unroll
        for (int k = 0; k < 16; k++) {
            const int kn = (k + 1) & 15;
            float bxv, byv, dB, vBx, vBy; bool iB;
            if (kn == 0) {            // compile-time under unroll
                bxv = s2x[0]; byv = s2y[0];
                dB = d0s; iB = i0s; vBx = v0x; vBy = v0y;
            } else {
                bxv = s2x[kn]; byv = s2y[kn];
                dB = clip_d(cl2, bxv, byv);
                iB = dB >= 0.0f;
                vin_of(cl2, bxv, byv, dB, iB, vBx, vBy);
            }
            // stage-3 edge (A,B): emit r0, r1
            float t  = dA * __builtin_amdgcn_rcpf(dA - dB);
            float Cx = fmaf(t, bxv - ax, ax);
            float Cy = fmaf(t, byv - ay, ay);
            bool cr = (iA != iB);
            float r0x = cr ? Cx : vAx, r0y = cr ? Cy : vAy;
            float r1x = vBx,           r1y = vBy;

            if (k == 0) {             // compile-time under unroll
                fsx = r0x; fsy = r0y;
                SINIT(r0x, r0y);
                PUSH(r1x, r1y, true);
            } else {
                PUSH(r0x, r0y, false);
                PUSH(r1x, r1y, false);
            }
            ax = bxv; ay = byv; dA = dB; iA = iB; vAx = vBx; vAy = vBy;
        }
        // wrap: stage-4 edge from last stage-3 output back to the first
        PUSH(fsx, fsy, false);
        // close the shoelace cycle
        acc = fmaf(opx, ofy, acc);
        acc = fmaf(-opy, ofx, acc);

        #undef PUSH
        #undef SINIT

        float area = fabsf(acc) * 0.5f;

        // ---- z overlap + volumes ----
        float zmax1 = z1 + dz1 * 0.5f, zmin1 = z1 - dz1 * 0.5f;
        float zmax2 = z2 + dz2 * 0.5f, zmin2 = z2 - dz2 * 0.5f;
        float zo = fmaxf(fminf(zmax1, zmax2) - fmaxf(zmin1, zmin2), 0.0f);
        float inter3d = area * zo;
        float vol1 = w1 * h1 * dz1;
        float vol2 = w2 * h2 * dz2;
        float union3d = vol1 + vol2 - inter3d;
        val = 1.0f - inter3d / union3d;
    }

    // ---- block reduction -> double atomic ----
    #pragma unroll
    for (int off = 32; off > 0; off >>= 1)
        val += __shfl_down(val, off, 64);
    __shared__ float wsum[4];
    int lane = threadIdx.x & 63, wid = threadIdx.x >> 6;
    if (lane == 0) wsum[wid] = val;
    __syncthreads();
    if (threadIdx.x == 0) {
        float s = wsum[0] + wsum[1] + wsum[2] + wsum[3];
        atomicAdd(acc_out, (double)s);
    }
}

__global__ void iou3d_finalize_kernel(const double* __restrict__ acc,
                                      float* __restrict__ out, int N)
{
    out[0] = (float)(acc[0] / (double)N);
}

extern "C" void kernel_launch(void* const* d_in, const int* in_sizes, int n_in,
                              void* d_out, int out_size, void* d_ws, size_t ws_size,
                              hipStream_t stream) {
    const float* pred   = (const float*)d_in[0];
    const float* target = (const float*)d_in[1];
    int N = in_sizes[0] / 7;
    double* acc = (double*)d_ws;

    hipMemsetAsync(d_ws, 0, sizeof(double), stream);

    int block = 256;
    int grid = (N + block - 1) / block;
    iou3d_loss_kernel<<<grid, block, 0, stream>>>(pred, target, acc, N);
    iou3d_finalize_kernel<<<1, 1, 0, stream>>>(acc, (float*)d_out, N);
}